// Round 1
// baseline (697.915 us; speedup 1.0000x reference)
//
#include <hip/hip_runtime.h>
#include <stdint.h>

// Problem dims (fixed by reference)
static constexpr int B  = 32;
static constexpr int T  = 350;
static constexpr int NIN = 2048;
static constexpr int NH  = 512;
static constexpr int NO  = 10;
static constexpr int BT  = B * T;

static constexpr float THETA = 10.0f;
static constexpr float BETA  = 0.36787944117144233f;   // e^-1 (refractory decay)
static constexpr float CREF  = 54.365636569180904707f; // SCALE_REF*THETA*e = 20e

// Workspace layout (bytes). Peak need ~52.9 MB.
static constexpr size_t OFF_W1T  = 0;                        // 2048*512 f32 = 4,194,304
static constexpr size_t OFF_MASK = 4194304;                  // BT*32 u64   = 2,867,200
static constexpr size_t OFF_SRM  = 7061504;                  // 128 f32
static constexpr size_t OFF_Z1   = 7062016;                  // BT*512 f32  = 22,937,600
static constexpr size_t OFF_A1   = 29999616;                 // BT*512 f32
static constexpr size_t OFF_Z2   = OFF_A1;                   // reuse (a1 dead after scan1)
static constexpr size_t OFF_A2   = OFF_A1 + (1u << 20);      // BT*10 f32 = 448,000

// --- srm_ext table: srm_ext[k] = srm[k-7] for 7<=k<107 else 0; srm[j]=(j/10)e^(1-j/10)
__global__ void k_init_srm(float* __restrict__ srm_ext) {
    int j = threadIdx.x;
    if (j < 128) {
        float v = 0.f;
        int i = j - 7;
        if (i >= 0 && i < 100) { float t = (float)i; v = (t * 0.1f) * expf(1.f - t * 0.1f); }
        srm_ext[j] = v;
    }
}

// --- W1 [512][2048] -> W1T [2048][512]
__global__ void k_transpose_w1(const float* __restrict__ W1, float* __restrict__ W1T) {
    __shared__ float tile[32][33];
    int n0 = blockIdx.x * 32, m0 = blockIdx.y * 32;
    int tx = threadIdx.x, ty0 = threadIdx.y; // block (32,8)
    #pragma unroll
    for (int i = 0; i < 4; ++i) {
        int ty = ty0 + 8 * i;
        tile[ty][tx] = W1[(size_t)(m0 + ty) * NIN + n0 + tx];
    }
    __syncthreads();
    #pragma unroll
    for (int i = 0; i < 4; ++i) {
        int ty = ty0 + 8 * i;
        W1T[(size_t)(n0 + ty) * NH + m0 + tx] = tile[tx][ty];
    }
}

// --- pack x [B][NIN][T] (0/1 f32) -> mask[b][t][nblk] (64 n-bits per word)
__global__ void k_pack(const float* __restrict__ x, uint64_t* __restrict__ mask) {
    int b = blockIdx.x, nblk = blockIdx.y;
    int wv = threadIdx.x >> 6, lane = threadIdx.x & 63;
    int n = nblk * 64 + lane;
    const float* xp = x + ((size_t)b * NIN + n) * T;
    for (int t = wv; t < T; t += 4) {
        float v = xp[t];
        uint64_t mk = __ballot(v != 0.0f);
        if (lane == 0) mask[((size_t)b * T + t) * 32 + nblk] = mk;
    }
}

// --- z1[b,t,:] = sum over active n of W1T[n,:]  (one wave per (b,t) column)
__global__ void __launch_bounds__(64) k_z1(const uint64_t* __restrict__ mask,
                                           const float* __restrict__ W1T,
                                           float* __restrict__ z1) {
    int row = blockIdx.x;          // b*T + t
    int lane = threadIdx.x;        // owns m = lane*8 .. lane*8+7
    const uint64_t* mrow = mask + (size_t)row * 32;
    float4 acc0 = {0, 0, 0, 0}, acc1 = {0, 0, 0, 0};
    for (int w = 0; w < 32; ++w) {
        uint64_t mk = mrow[w];
        while (mk) {
            int bit = __builtin_ctzll(mk);
            mk &= mk - 1;
            int n = (w << 6) + bit;
            const float4* cp = (const float4*)(W1T + (size_t)n * NH);
            float4 a = cp[lane * 2], c = cp[lane * 2 + 1];
            acc0.x += a.x; acc0.y += a.y; acc0.z += a.z; acc0.w += a.w;
            acc1.x += c.x; acc1.y += c.y; acc1.z += c.z; acc1.w += c.w;
        }
    }
    float4* zp = (float4*)(z1 + (size_t)row * NH);
    zp[lane * 2] = acc0; zp[lane * 2 + 1] = acc1;
}

// --- causal FIR over t, K=100 (truncated, matches reference exactly).
// thread <-> (b, m); 8 outputs per chunk via register tile; coeff table zero-padded.
__global__ void k_fir(const float* __restrict__ src, float* __restrict__ dst,
                      const float* __restrict__ srm_ext, int M) {
    int b = blockIdx.x;
    int t0_base = blockIdx.y * 32;
    int m = threadIdx.x;
    if (m >= M) return;
    for (int c = 0; c < 4; ++c) {
        int t0 = t0_base + c * 8;
        if (t0 >= T) break;
        float acc[8] = {0, 0, 0, 0, 0, 0, 0, 0};
        for (int d = 0; d <= 106; ++d) {
            int tau = t0 - 99 + d;
            float v = 0.f;
            if (tau >= 0 && tau < T) v = src[((size_t)b * T + tau) * M + m];
            #pragma unroll
            for (int r = 0; r < 8; ++r) acc[r] += srm_ext[r + 106 - d] * v; // srm[r+99-d]
        }
        #pragma unroll
        for (int r = 0; r < 8; ++r) {
            int t = t0 + r;
            if (t < T) dst[((size_t)b * T + t) * M + m] = acc[r];
        }
    }
}

// --- sequential spike scan with 2-state IIR refractory (exact to ~2e-11 vs kr=32 ref)
// m[t] = u[t] - 20e * B[t];  s=(m>=theta);  A[t]=s+beta*A[t-1];  B[t+1]=beta*(B[t]+A[t])
__global__ void k_scan(const float* __restrict__ u, float* __restrict__ s,
                       int M, int layout_tm) {
    int tid = blockIdx.x * blockDim.x + threadIdx.x;
    if (tid >= B * M) return;
    int b = tid / M, m = tid - b * M;
    const float* up = u + (size_t)b * T * M + m;
    float A = 0.f, Bs = 0.f;
    for (int t = 0; t < T; ++t) {
        float mem = up[(size_t)t * M] - CREF * Bs;
        float sp = (mem >= THETA) ? 1.0f : 0.0f;
        A = sp + BETA * A;
        Bs = BETA * (Bs + A);
        if (layout_tm) s[((size_t)b * T + t) * M + m] = sp;   // [b,t,m]
        else           s[((size_t)b * M + m) * T + t] = sp;   // [b,m,t] (output layout)
    }
}

// --- z2[b,t,o] = sum_m W2[o,m] * s1[b,t,m]   (one wave per (b,t) row, shfl reduce)
__global__ void __launch_bounds__(64) k_z2(const float* __restrict__ s1,
                                           const float* __restrict__ W2,
                                           float* __restrict__ z2) {
    int row = blockIdx.x;
    int lane = threadIdx.x;
    const float* sp = s1 + (size_t)row * NH;
    float acc[NO];
    #pragma unroll
    for (int o = 0; o < NO; ++o) acc[o] = 0.f;
    for (int j = 0; j < 8; ++j) {
        int m = lane + 64 * j;
        float sv = sp[m];
        #pragma unroll
        for (int o = 0; o < NO; ++o) acc[o] += sv * W2[(size_t)o * NH + m];
    }
    #pragma unroll
    for (int o = 0; o < NO; ++o) {
        float v = acc[o];
        for (int off = 32; off > 0; off >>= 1) v += __shfl_down(v, off);
        if (lane == 0) z2[(size_t)row * NO + o] = v;
    }
}

extern "C" void kernel_launch(void* const* d_in, const int* in_sizes, int n_in,
                              void* d_out, int out_size, void* d_ws, size_t ws_size,
                              hipStream_t stream) {
    const float* x  = (const float*)d_in[0];
    const float* W1 = (const float*)d_in[1];
    const float* W2 = (const float*)d_in[2];
    char* ws = (char*)d_ws;
    float*    W1T  = (float*)(ws + OFF_W1T);
    uint64_t* mask = (uint64_t*)(ws + OFF_MASK);
    float*    srm  = (float*)(ws + OFF_SRM);
    float*    z1   = (float*)(ws + OFF_Z1);
    float*    a1   = (float*)(ws + OFF_A1);
    float*    s1   = z1;                       // reuse: z1 dead after fir1
    float*    z2   = (float*)(ws + OFF_Z2);    // reuse: a1 dead after scan1
    float*    a2   = (float*)(ws + OFF_A2);
    float*    out  = (float*)d_out;

    hipLaunchKernelGGL(k_init_srm,     dim3(1),              dim3(128),   0, stream, srm);
    hipLaunchKernelGGL(k_transpose_w1, dim3(NIN/32, NH/32),  dim3(32, 8), 0, stream, W1, W1T);
    hipLaunchKernelGGL(k_pack,         dim3(B, NIN/64),      dim3(256),   0, stream, x, mask);
    hipLaunchKernelGGL(k_z1,           dim3(BT),             dim3(64),    0, stream, mask, W1T, z1);
    hipLaunchKernelGGL(k_fir,          dim3(B, 11),          dim3(512),   0, stream, z1, a1, srm, NH);
    hipLaunchKernelGGL(k_scan,         dim3((B*NH)/256),     dim3(256),   0, stream, a1, s1, NH, 1);
    hipLaunchKernelGGL(k_z2,           dim3(BT),             dim3(64),    0, stream, s1, W2, z2);
    hipLaunchKernelGGL(k_fir,          dim3(B, 11),          dim3(64),    0, stream, z2, a2, srm, NO);
    hipLaunchKernelGGL(k_scan,         dim3(2),              dim3(256),   0, stream, a2, out, NO, 0);
}

// Round 2
// 494.954 us; speedup vs baseline: 1.4101x; 1.4101x over previous
//
#include <hip/hip_runtime.h>
#include <stdint.h>

// Problem dims (fixed by reference)
static constexpr int B  = 32;
static constexpr int T  = 350;
static constexpr int NIN = 2048;
static constexpr int NH  = 512;
static constexpr int NO  = 10;
static constexpr int BT  = B * T;

static constexpr float THETA = 10.0f;
static constexpr float BETA  = 0.36787944117144233f;   // e^-1 (refractory decay)
static constexpr float CREF  = 54.365636569180904707f; // SCALE_REF*THETA*e = 20e

// Workspace layout (bytes). Peak need ~31 MB.
static constexpr size_t OFF_W1T  = 0;                        // 2048*512 f32 = 4,194,304
static constexpr size_t OFF_MASK = 4194304;                  // BT*32 u64   = 2,867,200
static constexpr size_t OFF_SRM  = 7061504;                  // 128 f32
static constexpr size_t OFF_Z1   = 7062016;                  // BT*512 f32  = 22,937,600
static constexpr size_t OFF_A1   = 29999616;                 // BT*512 f32
static constexpr size_t OFF_Z2   = OFF_A1;                   // reuse (a1 dead after scan1)
static constexpr size_t OFF_A2   = OFF_A1 + (1u << 20);      // BT*10 f32 = 448,000

// --- srm_ext table: srm_ext[k] = srm[k-7] for 7<=k<107 else 0; srm[j]=(j/10)e^(1-j/10)
__global__ void k_init_srm(float* __restrict__ srm_ext) {
    int j = threadIdx.x;
    if (j < 128) {
        float v = 0.f;
        int i = j - 7;
        if (i >= 0 && i < 100) { float t = (float)i; v = (t * 0.1f) * expf(1.f - t * 0.1f); }
        srm_ext[j] = v;
    }
}

// --- W1 [512][2048] -> W1T [2048][512]
__global__ void k_transpose_w1(const float* __restrict__ W1, float* __restrict__ W1T) {
    __shared__ float tile[32][33];
    int n0 = blockIdx.x * 32, m0 = blockIdx.y * 32;
    int tx = threadIdx.x, ty0 = threadIdx.y; // block (32,8)
    #pragma unroll
    for (int i = 0; i < 4; ++i) {
        int ty = ty0 + 8 * i;
        tile[ty][tx] = W1[(size_t)(m0 + ty) * NIN + n0 + tx];
    }
    __syncthreads();
    #pragma unroll
    for (int i = 0; i < 4; ++i) {
        int ty = ty0 + 8 * i;
        W1T[(size_t)(n0 + ty) * NH + m0 + tx] = tile[tx][ty];
    }
}

// --- pack x [B][NIN][T] (0/1 f32) -> mask[b][t][nblk] (64 n-bits per word)
__global__ void k_pack(const float* __restrict__ x, uint64_t* __restrict__ mask) {
    int b = blockIdx.x, nblk = blockIdx.y;
    int wv = threadIdx.x >> 6, lane = threadIdx.x & 63;
    int n = nblk * 64 + lane;
    const float* xp = x + ((size_t)b * NIN + n) * T;
    for (int t = wv; t < T; t += 4) {
        float v = xp[t];
        uint64_t mk = __ballot(v != 0.0f);
        if (lane == 0) mask[((size_t)b * T + t) * 32 + nblk] = mk;
    }
}

// --- z1[b,t,:] = sum over active n of W1T[n,:]  (one wave per (b,t) column)
__global__ void __launch_bounds__(64) k_z1(const uint64_t* __restrict__ mask,
                                           const float* __restrict__ W1T,
                                           float* __restrict__ z1) {
    int row = blockIdx.x;          // b*T + t
    int lane = threadIdx.x;        // owns m = lane*8 .. lane*8+7
    const uint64_t* mrow = mask + (size_t)row * 32;
    float4 acc0 = {0, 0, 0, 0}, acc1 = {0, 0, 0, 0};
    for (int w = 0; w < 32; ++w) {
        uint64_t mk = mrow[w];
        while (mk) {
            int bit = __builtin_ctzll(mk);
            mk &= mk - 1;
            int n = (w << 6) + bit;
            const float4* cp = (const float4*)(W1T + (size_t)n * NH);
            float4 a = cp[lane * 2], c = cp[lane * 2 + 1];
            acc0.x += a.x; acc0.y += a.y; acc0.z += a.z; acc0.w += a.w;
            acc1.x += c.x; acc1.y += c.y; acc1.z += c.z; acc1.w += c.w;
        }
    }
    float4* zp = (float4*)(z1 + (size_t)row * NH);
    zp[lane * 2] = acc0; zp[lane * 2 + 1] = acc1;
}

// --- causal FIR over t, K=100 (truncated, matches reference exactly).
__global__ void k_fir(const float* __restrict__ src, float* __restrict__ dst,
                      const float* __restrict__ srm_ext, int M) {
    int b = blockIdx.x;
    int t0_base = blockIdx.y * 32;
    int m = threadIdx.x;
    if (m >= M) return;
    for (int c = 0; c < 4; ++c) {
        int t0 = t0_base + c * 8;
        if (t0 >= T) break;
        float acc[8] = {0, 0, 0, 0, 0, 0, 0, 0};
        for (int d = 0; d <= 106; ++d) {
            int tau = t0 - 99 + d;
            float v = 0.f;
            if (tau >= 0 && tau < T) v = src[((size_t)b * T + tau) * M + m];
            #pragma unroll
            for (int r = 0; r < 8; ++r) acc[r] += srm_ext[r + 106 - d] * v; // srm[r+99-d]
        }
        #pragma unroll
        for (int r = 0; r < 8; ++r) {
            int t = t0 + r;
            if (t < T) dst[((size_t)b * T + t) * M + m] = acc[r];
        }
    }
}

// --- sequential spike scan, chunked double-buffered register prefetch.
// m[t] = u[t] - 20e * B[t];  s=(m>=theta);  A[t]=s+beta*A[t-1];  B[t+1]=beta*(B[t]+A[t])
// Loads of u are state-independent: prefetch chunk c+1 while computing chunk c.
template<int M, int LAYOUT_TM>
__global__ void k_scan_t(const float* __restrict__ u, float* __restrict__ s) {
    constexpr int CT = 16;
    constexpr int NC = (T + CT - 1) / CT;   // 22 (last chunk = 14 steps)
    int tid = blockIdx.x * blockDim.x + threadIdx.x;
    if (tid >= B * M) return;
    int b = tid / M, m = tid - b * M;
    const float* up = u + (size_t)b * T * M + m;
    float cur[CT], nxt[CT];
    float A = 0.f, Bs = 0.f;
    #pragma unroll
    for (int j = 0; j < CT; ++j) cur[j] = up[(size_t)j * M];   // chunk 0
    for (int c = 0; c < NC; ++c) {
        int t0 = c * CT;
        int nsteps = (T - t0 < CT) ? (T - t0) : CT;
        if (c + 1 < NC) {
            int t1 = t0 + CT;
            #pragma unroll
            for (int j = 0; j < CT; ++j) {
                int t = t1 + j;
                nxt[j] = (t < T) ? up[(size_t)t * M] : 0.f;
            }
        }
        float outbuf[CT];
        #pragma unroll
        for (int j = 0; j < CT; ++j) {
            if (j < nsteps) {
                float mem = cur[j] - CREF * Bs;
                float sp = (mem >= THETA) ? 1.0f : 0.0f;
                A = sp + BETA * A;
                Bs = BETA * (Bs + A);
                if (LAYOUT_TM) s[((size_t)b * T + (t0 + j)) * M + m] = sp; // coalesced
                else           outbuf[j] = sp;
            }
        }
        if (!LAYOUT_TM) {
            #pragma unroll
            for (int j = 0; j < CT; ++j)
                if (j < nsteps) s[((size_t)(b * M + m)) * T + t0 + j] = outbuf[j];
        }
        #pragma unroll
        for (int j = 0; j < CT; ++j) cur[j] = nxt[j];
    }
}

// --- z2[b,t,o] = sum_m W2[o,m] * s1[b,t,m]   (one wave per (b,t) row, shfl reduce)
__global__ void __launch_bounds__(64) k_z2(const float* __restrict__ s1,
                                           const float* __restrict__ W2,
                                           float* __restrict__ z2) {
    int row = blockIdx.x;
    int lane = threadIdx.x;
    const float* sp = s1 + (size_t)row * NH;
    float acc[NO];
    #pragma unroll
    for (int o = 0; o < NO; ++o) acc[o] = 0.f;
    for (int j = 0; j < 8; ++j) {
        int m = lane + 64 * j;
        float sv = sp[m];
        #pragma unroll
        for (int o = 0; o < NO; ++o) acc[o] += sv * W2[(size_t)o * NH + m];
    }
    #pragma unroll
    for (int o = 0; o < NO; ++o) {
        float v = acc[o];
        for (int off = 32; off > 0; off >>= 1) v += __shfl_down(v, off);
        if (lane == 0) z2[(size_t)row * NO + o] = v;
    }
}

extern "C" void kernel_launch(void* const* d_in, const int* in_sizes, int n_in,
                              void* d_out, int out_size, void* d_ws, size_t ws_size,
                              hipStream_t stream) {
    const float* x  = (const float*)d_in[0];
    const float* W1 = (const float*)d_in[1];
    const float* W2 = (const float*)d_in[2];
    char* ws = (char*)d_ws;
    float*    W1T  = (float*)(ws + OFF_W1T);
    uint64_t* mask = (uint64_t*)(ws + OFF_MASK);
    float*    srm  = (float*)(ws + OFF_SRM);
    float*    z1   = (float*)(ws + OFF_Z1);
    float*    a1   = (float*)(ws + OFF_A1);
    float*    s1   = z1;                       // reuse: z1 dead after fir1
    float*    z2   = (float*)(ws + OFF_Z2);    // reuse: a1 dead after scan1
    float*    a2   = (float*)(ws + OFF_A2);
    float*    out  = (float*)d_out;

    hipLaunchKernelGGL(k_init_srm,     dim3(1),              dim3(128),   0, stream, srm);
    hipLaunchKernelGGL(k_transpose_w1, dim3(NIN/32, NH/32),  dim3(32, 8), 0, stream, W1, W1T);
    hipLaunchKernelGGL(k_pack,         dim3(B, NIN/64),      dim3(256),   0, stream, x, mask);
    hipLaunchKernelGGL(k_z1,           dim3(BT),             dim3(64),    0, stream, mask, W1T, z1);
    hipLaunchKernelGGL(k_fir,          dim3(B, 11),          dim3(512),   0, stream, z1, a1, srm, NH);
    hipLaunchKernelGGL((k_scan_t<NH, 1>), dim3((B*NH)/64),   dim3(64),    0, stream, a1, s1);
    hipLaunchKernelGGL(k_z2,           dim3(BT),             dim3(64),    0, stream, s1, W2, z2);
    hipLaunchKernelGGL(k_fir,          dim3(B, 11),          dim3(64),    0, stream, z2, a2, srm, NO);
    hipLaunchKernelGGL((k_scan_t<NO, 0>), dim3(5),           dim3(64),    0, stream, a2, out);
}

// Round 3
// 377.057 us; speedup vs baseline: 1.8510x; 1.3127x over previous
//
#include <hip/hip_runtime.h>
#include <stdint.h>

// Problem dims (fixed by reference)
static constexpr int B  = 32;
static constexpr int T  = 350;
static constexpr int NIN = 2048;
static constexpr int NH  = 512;
static constexpr int NO  = 10;
static constexpr int BT  = B * T;

static constexpr float THETA = 10.0f;
static constexpr float BETA  = 0.36787944117144233f;   // e^-1 (refractory decay)
static constexpr float CREF  = 54.365636569180904707f; // SCALE_REF*THETA*e = 20e

// Workspace layout (bytes). Peak need ~31.5 MB.
static constexpr size_t OFF_W1T  = 0;                        // 2048*512 f32 = 4,194,304
static constexpr size_t OFF_MASK = 4194304;                  // BT*32 u64   = 2,867,200
static constexpr size_t OFF_SRM  = 7061504;                  // 160 f32 (1KB slot)
static constexpr size_t OFF_Z1   = 7062528;                  // BT*512 f32  = 22,937,600
static constexpr size_t OFF_A1   = 30000128;                 // BT*512 f32
static constexpr size_t OFF_Z2   = OFF_A1;                   // reuse (a1 dead after scan1)
static constexpr size_t OFF_A2   = OFF_A1 + (1u << 20);      // BT*10 f32 = 448,000

// --- srm_ext table, offset 15: srm_ext[k] = srm[k-15] for 15<=k<115 else 0
//     srm[j] = (j/10) e^(1 - j/10)
__global__ void k_init_srm(float* __restrict__ srm_ext) {
    int j = threadIdx.x;
    if (j < 160) {
        float v = 0.f;
        int i = j - 15;
        if (i >= 0 && i < 100) { float t = (float)i; v = (t * 0.1f) * expf(1.f - t * 0.1f); }
        srm_ext[j] = v;
    }
}

// --- W1 [512][2048] -> W1T [2048][512]
__global__ void k_transpose_w1(const float* __restrict__ W1, float* __restrict__ W1T) {
    __shared__ float tile[32][33];
    int n0 = blockIdx.x * 32, m0 = blockIdx.y * 32;
    int tx = threadIdx.x, ty0 = threadIdx.y; // block (32,8)
    #pragma unroll
    for (int i = 0; i < 4; ++i) {
        int ty = ty0 + 8 * i;
        tile[ty][tx] = W1[(size_t)(m0 + ty) * NIN + n0 + tx];
    }
    __syncthreads();
    #pragma unroll
    for (int i = 0; i < 4; ++i) {
        int ty = ty0 + 8 * i;
        W1T[(size_t)(n0 + ty) * NH + m0 + tx] = tile[tx][ty];
    }
}

// --- pack v2: coalesced t-reads + 64x64 bit transpose.
// Block = (b, nblk of 64 n). Phase 1: wave reads 64 consecutive t for one n,
// ballot -> t-mask word; store to LDS[chunk][n]. Phase 2: bit-transpose so
// lane=t holds the 64-bit n-mask; write mask[b][t][nblk].
__global__ void __launch_bounds__(256) k_pack(const float* __restrict__ x,
                                              uint64_t* __restrict__ mask) {
    __shared__ uint64_t tb[6][64];
    int b = blockIdx.x, nblk = blockIdx.y;
    int wv = threadIdx.x >> 6, lane = threadIdx.x & 63;
    for (int nr = wv; nr < 64; nr += 4) {
        const float* xp = x + ((size_t)b * NIN + nblk * 64 + nr) * T;
        #pragma unroll
        for (int c = 0; c < 6; ++c) {
            int t = c * 64 + lane;
            float v = (t < T) ? xp[t] : 0.f;
            uint64_t mk = __ballot(v != 0.0f);
            if (lane == 0) tb[c][nr] = mk;
        }
    }
    __syncthreads();
    static const uint64_t AM[6] = {
        0x00000000FFFFFFFFull, 0x0000FFFF0000FFFFull, 0x00FF00FF00FF00FFull,
        0x0F0F0F0F0F0F0F0Full, 0x3333333333333333ull, 0x5555555555555555ull };
    for (int c = wv; c < 6; c += 4) {
        uint64_t w = tb[c][lane];            // lane = n, bits = t
        #pragma unroll
        for (int i = 0; i < 6; ++i) {
            int s = 32 >> i;
            uint64_t A = AM[i];
            uint64_t y = __shfl_xor((unsigned long long)w, s);
            if ((lane & s) == 0) w = (w & A)  | ((y & A) << s);
            else                 w = (w & ~A) | ((y & ~A) >> s);
        }
        int t = c * 64 + lane;               // lane = t, bits = n
        if (t < T) mask[((size_t)b * T + t) * 32 + nblk] = w;
    }
}

// --- z1[b,t,:] = sum over active n of W1T[n,:]  (one wave per (b,t) column)
__global__ void __launch_bounds__(64) k_z1(const uint64_t* __restrict__ mask,
                                           const float* __restrict__ W1T,
                                           float* __restrict__ z1) {
    int row = blockIdx.x;          // b*T + t
    int lane = threadIdx.x;        // owns m = lane*8 .. lane*8+7
    const uint64_t* mrow = mask + (size_t)row * 32;
    float4 acc0 = {0, 0, 0, 0}, acc1 = {0, 0, 0, 0};
    for (int w = 0; w < 32; ++w) {
        uint64_t mk = mrow[w];
        while (mk) {
            int bit = __builtin_ctzll(mk);
            mk &= mk - 1;
            int n = (w << 6) + bit;
            const float4* cp = (const float4*)(W1T + (size_t)n * NH);
            float4 a = cp[lane * 2], c = cp[lane * 2 + 1];
            acc0.x += a.x; acc0.y += a.y; acc0.z += a.z; acc0.w += a.w;
            acc1.x += c.x; acc1.y += c.y; acc1.z += c.z; acc1.w += c.w;
        }
    }
    float4* zp = (float4*)(z1 + (size_t)row * NH);
    zp[lane * 2] = acc0; zp[lane * 2 + 1] = acc1;
}

// --- FIR v2 for M=512: wave = (b, m-group of 64, t-tile of 16).
// Register-rolling coefficient window (1 uniform load/iter) + depth-2 src
// prefetch (independent loads in flight). Exact truncated K=100 kernel.
__global__ void __launch_bounds__(64) k_fir1(const float* __restrict__ src,
                                             float* __restrict__ dst,
                                             const float* __restrict__ srm_ext) {
    constexpr int TT = 16;
    constexpr int NTAU = 99 + TT;            // 115
    int b = blockIdx.x, mg = blockIdx.y, tg = blockIdx.z;
    int m = mg * 64 + (int)threadIdx.x;
    int t0 = tg * TT;
    const float* sp = src + (size_t)b * T * NH + m;

    float acc[TT];
    #pragma unroll
    for (int r = 0; r < TT; ++r) acc[r] = 0.f;
    float c[TT];
    #pragma unroll
    for (int r = 0; r < TT; ++r) c[r] = srm_ext[r + 114];   // c[r]=srm[t0+r-tau] at dd=0

    auto ld = [&](int dd) -> float {
        int tau = t0 - 99 + dd;
        return (tau >= 0 && tau < T) ? sp[(size_t)tau * NH] : 0.f;
    };
    float v0 = ld(0), v1 = ld(1);
    #pragma unroll 5
    for (int dd = 0; dd < NTAU; ++dd) {
        float vn = (dd + 2 < NTAU) ? ld(dd + 2) : 0.f;
        float c0 = (dd + 1 < NTAU) ? srm_ext[113 - dd] : 0.f;
        #pragma unroll
        for (int r = 0; r < TT; ++r) acc[r] += c[r] * v0;
        #pragma unroll
        for (int r = TT - 1; r > 0; --r) c[r] = c[r - 1];
        c[0] = c0;
        v0 = v1; v1 = vn;
    }
    #pragma unroll
    for (int r = 0; r < TT; ++r) {
        int t = t0 + r;
        if (t < T) dst[((size_t)b * T + t) * NH + m] = acc[r];
    }
}

// --- small FIR (layer 2, M=10): original register-tile version.
__global__ void k_fir(const float* __restrict__ src, float* __restrict__ dst,
                      const float* __restrict__ srm_ext, int M) {
    int b = blockIdx.x;
    int t0_base = blockIdx.y * 32;
    int m = threadIdx.x;
    if (m >= M) return;
    for (int cch = 0; cch < 4; ++cch) {
        int t0 = t0_base + cch * 8;
        if (t0 >= T) break;
        float acc[8] = {0, 0, 0, 0, 0, 0, 0, 0};
        for (int d = 0; d <= 106; ++d) {
            int tau = t0 - 99 + d;
            float v = 0.f;
            if (tau >= 0 && tau < T) v = src[((size_t)b * T + tau) * M + m];
            #pragma unroll
            for (int r = 0; r < 8; ++r) acc[r] += srm_ext[r + 114 - d] * v; // srm[r+99-d]
        }
        #pragma unroll
        for (int r = 0; r < 8; ++r) {
            int t = t0 + r;
            if (t < T) dst[((size_t)b * T + t) * M + m] = acc[r];
        }
    }
}

// --- sequential spike scan, chunked double-buffered register prefetch.
template<int M, int LAYOUT_TM>
__global__ void k_scan_t(const float* __restrict__ u, float* __restrict__ s) {
    constexpr int CT = 16;
    constexpr int NC = (T + CT - 1) / CT;   // 22
    int tid = blockIdx.x * blockDim.x + threadIdx.x;
    if (tid >= B * M) return;
    int b = tid / M, m = tid - b * M;
    const float* up = u + (size_t)b * T * M + m;
    float cur[CT], nxt[CT];
    float A = 0.f, Bs = 0.f;
    #pragma unroll
    for (int j = 0; j < CT; ++j) cur[j] = up[(size_t)j * M];
    for (int c = 0; c < NC; ++c) {
        int t0 = c * CT;
        int nsteps = (T - t0 < CT) ? (T - t0) : CT;
        if (c + 1 < NC) {
            int t1 = t0 + CT;
            #pragma unroll
            for (int j = 0; j < CT; ++j) {
                int t = t1 + j;
                nxt[j] = (t < T) ? up[(size_t)t * M] : 0.f;
            }
        }
        float outbuf[CT];
        #pragma unroll
        for (int j = 0; j < CT; ++j) {
            if (j < nsteps) {
                float mem = cur[j] - CREF * Bs;
                float sp = (mem >= THETA) ? 1.0f : 0.0f;
                A = sp + BETA * A;
                Bs = BETA * (Bs + A);
                if (LAYOUT_TM) s[((size_t)b * T + (t0 + j)) * M + m] = sp;
                else           outbuf[j] = sp;
            }
        }
        if (!LAYOUT_TM) {
            #pragma unroll
            for (int j = 0; j < CT; ++j)
                if (j < nsteps) s[((size_t)(b * M + m)) * T + t0 + j] = outbuf[j];
        }
        #pragma unroll
        for (int j = 0; j < CT; ++j) cur[j] = nxt[j];
    }
}

// --- z2[b,t,o] = sum_m W2[o,m] * s1[b,t,m]   (one wave per (b,t) row)
__global__ void __launch_bounds__(64) k_z2(const float* __restrict__ s1,
                                           const float* __restrict__ W2,
                                           float* __restrict__ z2) {
    int row = blockIdx.x;
    int lane = threadIdx.x;
    const float* sp = s1 + (size_t)row * NH;
    float acc[NO];
    #pragma unroll
    for (int o = 0; o < NO; ++o) acc[o] = 0.f;
    for (int j = 0; j < 8; ++j) {
        int m = lane + 64 * j;
        float sv = sp[m];
        #pragma unroll
        for (int o = 0; o < NO; ++o) acc[o] += sv * W2[(size_t)o * NH + m];
    }
    #pragma unroll
    for (int o = 0; o < NO; ++o) {
        float v = acc[o];
        for (int off = 32; off > 0; off >>= 1) v += __shfl_down(v, off);
        if (lane == 0) z2[(size_t)row * NO + o] = v;
    }
}

extern "C" void kernel_launch(void* const* d_in, const int* in_sizes, int n_in,
                              void* d_out, int out_size, void* d_ws, size_t ws_size,
                              hipStream_t stream) {
    const float* x  = (const float*)d_in[0];
    const float* W1 = (const float*)d_in[1];
    const float* W2 = (const float*)d_in[2];
    char* ws = (char*)d_ws;
    float*    W1T  = (float*)(ws + OFF_W1T);
    uint64_t* mask = (uint64_t*)(ws + OFF_MASK);
    float*    srm  = (float*)(ws + OFF_SRM);
    float*    z1   = (float*)(ws + OFF_Z1);
    float*    a1   = (float*)(ws + OFF_A1);
    float*    s1   = z1;                       // reuse: z1 dead after fir1
    float*    z2   = (float*)(ws + OFF_Z2);    // reuse: a1 dead after scan1
    float*    a2   = (float*)(ws + OFF_A2);
    float*    out  = (float*)d_out;

    hipLaunchKernelGGL(k_init_srm,     dim3(1),              dim3(256),   0, stream, srm);
    hipLaunchKernelGGL(k_transpose_w1, dim3(NIN/32, NH/32),  dim3(32, 8), 0, stream, W1, W1T);
    hipLaunchKernelGGL(k_pack,         dim3(B, NIN/64),      dim3(256),   0, stream, x, mask);
    hipLaunchKernelGGL(k_z1,           dim3(BT),             dim3(64),    0, stream, mask, W1T, z1);
    hipLaunchKernelGGL(k_fir1,         dim3(B, NH/64, 22),   dim3(64),    0, stream, z1, a1, srm);
    hipLaunchKernelGGL((k_scan_t<NH, 1>), dim3((B*NH)/64),   dim3(64),    0, stream, a1, s1);
    hipLaunchKernelGGL(k_z2,           dim3(BT),             dim3(64),    0, stream, s1, W2, z2);
    hipLaunchKernelGGL(k_fir,          dim3(B, 11),          dim3(64),    0, stream, z2, a2, srm, NO);
    hipLaunchKernelGGL((k_scan_t<NO, 0>), dim3(5),           dim3(64),    0, stream, a2, out);
}

// Round 4
// 342.882 us; speedup vs baseline: 2.0354x; 1.0997x over previous
//
#include <hip/hip_runtime.h>
#include <stdint.h>

static constexpr int B  = 32;
static constexpr int T  = 350;
static constexpr int NIN = 2048;
static constexpr int NH  = 512;
static constexpr int NO  = 10;
static constexpr int BT  = B * T;

static constexpr float THETA = 10.0f;
static constexpr float BETA  = 0.36787944117144233f;   // e^-1 (refractory decay)
static constexpr float CREF  = 54.365636569180904707f; // SCALE_REF*THETA*e = 20e

// Workspace layout (bytes). Peak ~52.94 MB (same as prior rounds).
static constexpr size_t OFF_W1T  = 0;                   // 2049*512 f32 (row 2048 = zeros)
static constexpr size_t OFF_MASK = 4196352;             // BT*32 u64 = 2,867,200
static constexpr size_t OFF_SRM  = 7063552;             // 192 f32 (offset-28 table)
static constexpr size_t OFF_Z1   = 7064576;             // BT*512 f32 = 22,937,600
static constexpr size_t OFF_A1   = 30002176;            // BT*512 f32
static constexpr size_t OFF_Z2   = OFF_A1;              // reuse (a1 dead when z2 written)

// ============ k_prep: pack (blocks 0..1023) + W1 transpose (1024..2047) + tables (2048)
// srm table offset-28: tb[k] = srm[k-28] for 28<=k<128 else 0; srm[j]=(j/10)e^(1-j/10)
__global__ void __launch_bounds__(256) k_prep(const float* __restrict__ x,
                                              const float* __restrict__ W1,
                                              float* __restrict__ W1T,
                                              uint64_t* __restrict__ mask,
                                              float* __restrict__ srm28) {
    int bid = blockIdx.x;
    if (bid < 1024) {
        // --- pack x [B][NIN][T] -> mask[b][t][nblk], coalesced + 64x64 bit transpose
        __shared__ uint64_t tb[6][64];
        int b = bid >> 5, nblk = bid & 31;
        int wv = threadIdx.x >> 6, lane = threadIdx.x & 63;
        for (int nr = wv; nr < 64; nr += 4) {
            const float* xp = x + ((size_t)b * NIN + nblk * 64 + nr) * T;
            #pragma unroll
            for (int c = 0; c < 6; ++c) {
                int t = c * 64 + lane;
                float v = (t < T) ? xp[t] : 0.f;
                uint64_t mk = __ballot(v != 0.0f);
                if (lane == 0) tb[c][nr] = mk;
            }
        }
        __syncthreads();
        static const uint64_t AM[6] = {
            0x00000000FFFFFFFFull, 0x0000FFFF0000FFFFull, 0x00FF00FF00FF00FFull,
            0x0F0F0F0F0F0F0F0Full, 0x3333333333333333ull, 0x5555555555555555ull };
        for (int c = wv; c < 6; c += 4) {
            uint64_t w = tb[c][lane];            // lane = n, bits = t
            #pragma unroll
            for (int i = 0; i < 6; ++i) {
                int s = 32 >> i;
                uint64_t A = AM[i];
                uint64_t y = __shfl_xor((unsigned long long)w, s);
                if ((lane & s) == 0) w = (w & A)  | ((y & A) << s);
                else                 w = (w & ~A) | ((y & ~A) >> s);
            }
            int t = c * 64 + lane;               // lane = t, bits = n
            if (t < T) mask[((size_t)b * T + t) * 32 + nblk] = w;
        }
    } else if (bid < 2048) {
        // --- W1 [512][2048] -> W1T [2048][512]
        __shared__ float tile[32][33];
        int idx = bid - 1024;
        int n0 = (idx & 63) * 32, m0 = (idx >> 6) * 32;
        int tx = threadIdx.x & 31, ty0 = threadIdx.x >> 5;   // (32,8)
        #pragma unroll
        for (int i = 0; i < 4; ++i) {
            int ty = ty0 + 8 * i;
            tile[ty][tx] = W1[(size_t)(m0 + ty) * NIN + n0 + tx];
        }
        __syncthreads();
        #pragma unroll
        for (int i = 0; i < 4; ++i) {
            int ty = ty0 + 8 * i;
            W1T[(size_t)(n0 + ty) * NH + m0 + tx] = tile[tx][ty];
        }
    } else {
        // --- srm table + zero row 2048 of W1T (gather pad target)
        int j = threadIdx.x;
        if (j < 192) {
            float v = 0.f;
            int i = j - 28;
            if (i >= 0 && i < 100) { float t = (float)i; v = (t * 0.1f) * expf(1.f - t * 0.1f); }
            srm28[j] = v;
        }
        for (int i = j; i < NH; i += 256) W1T[(size_t)2048 * NH + i] = 0.f;
    }
}

// ============ k_z1: z1[b,t,:] = sum over active n of W1T[n,:]
// Phase A: decode mask -> LDS index list (padded x4 with zero-row 2048).
// Phase B: 4 n per iteration -> 8 independent dwordx4 loads in flight.
__global__ void __launch_bounds__(64) k_z1(const uint64_t* __restrict__ mask,
                                           const float* __restrict__ W1T,
                                           float* __restrict__ z1) {
    __shared__ alignas(8) uint16_t lst[288];
    int row = blockIdx.x, lane = threadIdx.x;
    const uint64_t* mrow = mask + (size_t)row * 32;
    uint64_t w = (lane < 32) ? mrow[lane] : 0ull;
    int cnt = __popcll(w);
    int pre = cnt;
    #pragma unroll
    for (int off = 1; off < 64; off <<= 1) {
        int v = __shfl_up(pre, off);
        if (lane >= off) pre += v;
    }
    int total = __shfl(pre, 63);
    int excl = pre - cnt;
    while (w) {
        int bit = __builtin_ctzll(w);
        w &= w - 1;
        lst[excl++] = (uint16_t)((lane << 6) + bit);
    }
    int padded = (total + 3) & ~3;
    if (lane < padded - total) lst[total + lane] = 2048;   // zero row
    __syncthreads();

    const float4* W4 = (const float4*)W1T;
    float4 a0 = {0,0,0,0}, a1v = {0,0,0,0};
    int i0 = lane * 2, i1 = lane * 2 + 1;
    for (int k = 0; k < padded; k += 4) {
        ushort4 q = *(const ushort4*)(lst + k);
        const float4* p0 = W4 + (size_t)q.x * 128;
        const float4* p1 = W4 + (size_t)q.y * 128;
        const float4* p2 = W4 + (size_t)q.z * 128;
        const float4* p3 = W4 + (size_t)q.w * 128;
        float4 x0 = p0[i0], y0 = p0[i1];
        float4 x1 = p1[i0], y1 = p1[i1];
        float4 x2 = p2[i0], y2 = p2[i1];
        float4 x3 = p3[i0], y3 = p3[i1];
        // ascending-n order preserved -> bit-exact vs previous rounds
        a0.x += x0.x; a0.y += x0.y; a0.z += x0.z; a0.w += x0.w;
        a1v.x += y0.x; a1v.y += y0.y; a1v.z += y0.z; a1v.w += y0.w;
        a0.x += x1.x; a0.y += x1.y; a0.z += x1.z; a0.w += x1.w;
        a1v.x += y1.x; a1v.y += y1.y; a1v.z += y1.z; a1v.w += y1.w;
        a0.x += x2.x; a0.y += x2.y; a0.z += x2.z; a0.w += x2.w;
        a1v.x += y2.x; a1v.y += y2.y; a1v.z += y2.z; a1v.w += y2.w;
        a0.x += x3.x; a0.y += x3.y; a0.z += x3.z; a0.w += x3.w;
        a1v.x += y3.x; a1v.y += y3.y; a1v.z += y3.z; a1v.w += y3.w;
    }
    float4* zp = (float4*)(z1 + (size_t)row * NH);
    zp[i0] = a0; zp[i1] = a1v;
}

// ============ k_fir1: causal FIR K=100, M=512. float4 lanes (wave covers 256 m),
// 16-out register tile, taps padded to 128 with exact-zero coeffs, inner-16 full
// unroll so the coefficient window shifts become register renaming.
__global__ void __launch_bounds__(64) k_fir1(const float* __restrict__ src,
                                             float* __restrict__ dst,
                                             const float* __restrict__ srm28) {
    __shared__ float tb[192];
    int b = blockIdx.x, half = blockIdx.y, tg = blockIdx.z;
    int lane = threadIdx.x;
    for (int i = lane; i < 192; i += 64) tb[i] = srm28[i];
    __syncthreads();
    int t0 = tg * 16;
    int m = half * 256 + lane * 4;
    const float* sp = src + (size_t)b * T * NH + m;

    float4 acc[16];
    #pragma unroll
    for (int r = 0; r < 16; ++r) acc[r] = make_float4(0.f, 0.f, 0.f, 0.f);
    float c[16];
    #pragma unroll
    for (int r = 0; r < 16; ++r) c[r] = tb[r + 127];     // c_r(dd=0) = srm[r+99]

    for (int o = 0; o < 8; ++o) {
        #pragma unroll
        for (int j = 0; j < 16; ++j) {
            int dd = o * 16 + j;
            int tau = t0 - 99 + dd;
            float4 v = make_float4(0.f, 0.f, 0.f, 0.f);
            if (tau >= 0 && tau < T) v = *(const float4*)(sp + (size_t)tau * NH);
            #pragma unroll
            for (int r = 0; r < 16; ++r) {
                acc[r].x += c[r] * v.x; acc[r].y += c[r] * v.y;
                acc[r].z += c[r] * v.z; acc[r].w += c[r] * v.w;
            }
            #pragma unroll
            for (int r = 15; r > 0; --r) c[r] = c[r - 1];  // renamed under unroll
            int ci = 126 - dd;
            c[0] = tb[ci < 0 ? 0 : ci];
        }
    }
    #pragma unroll
    for (int r = 0; r < 16; ++r) {
        int t = t0 + r;
        if (t < T) *(float4*)(dst + ((size_t)b * T + t) * NH + m) = acc[r];
    }
}

// ============ scan layer 1: chunked double-buffered register prefetch
template<int M, int LAYOUT_TM>
__global__ void k_scan_t(const float* __restrict__ u, float* __restrict__ s) {
    constexpr int CT = 16;
    constexpr int NC = (T + CT - 1) / CT;
    int tid = blockIdx.x * blockDim.x + threadIdx.x;
    if (tid >= B * M) return;
    int b = tid / M, m = tid - b * M;
    const float* up = u + (size_t)b * T * M + m;
    float cur[CT], nxt[CT];
    float A = 0.f, Bs = 0.f;
    #pragma unroll
    for (int j = 0; j < CT; ++j) cur[j] = up[(size_t)j * M];
    for (int c = 0; c < NC; ++c) {
        int t0 = c * CT;
        int nsteps = (T - t0 < CT) ? (T - t0) : CT;
        if (c + 1 < NC) {
            int t1 = t0 + CT;
            #pragma unroll
            for (int j = 0; j < CT; ++j) {
                int t = t1 + j;
                nxt[j] = (t < T) ? up[(size_t)t * M] : 0.f;
            }
        }
        float outbuf[CT];
        #pragma unroll
        for (int j = 0; j < CT; ++j) {
            if (j < nsteps) {
                float mem = cur[j] - CREF * Bs;
                float sp = (mem >= THETA) ? 1.0f : 0.0f;
                A = sp + BETA * A;
                Bs = BETA * (Bs + A);
                if (LAYOUT_TM) s[((size_t)b * T + (t0 + j)) * M + m] = sp;
                else           outbuf[j] = sp;
            }
        }
        if (!LAYOUT_TM) {
            #pragma unroll
            for (int j = 0; j < CT; ++j)
                if (j < nsteps) s[((size_t)(b * M + m)) * T + t0 + j] = outbuf[j];
        }
        #pragma unroll
        for (int j = 0; j < CT; ++j) cur[j] = nxt[j];
    }
}

// ============ k_z2: z2[b,t,o] = sum_m W2[o,m] * s1[b,t,m] (wave per (b,t) row)
__global__ void __launch_bounds__(64) k_z2(const float* __restrict__ s1,
                                           const float* __restrict__ W2,
                                           float* __restrict__ z2) {
    int row = blockIdx.x;
    int lane = threadIdx.x;
    const float* sp = s1 + (size_t)row * NH;
    float acc[NO];
    #pragma unroll
    for (int o = 0; o < NO; ++o) acc[o] = 0.f;
    for (int j = 0; j < 8; ++j) {
        int m = lane + 64 * j;
        float sv = sp[m];
        #pragma unroll
        for (int o = 0; o < NO; ++o) acc[o] += sv * W2[(size_t)o * NH + m];
    }
    #pragma unroll
    for (int o = 0; o < NO; ++o) {
        float v = acc[o];
        for (int off = 32; off > 0; off >>= 1) v += __shfl_down(v, off);
        if (lane == 0) z2[(size_t)row * NO + o] = v;
    }
}

// ============ k_fir2scan: layer-2 FIR (z2 in LDS) + refractory scan + output
// block = one b, 256 threads. fir threads: tid<220 -> (tt=tid/10, o=tid%10).
__global__ void __launch_bounds__(256) k_fir2scan(const float* __restrict__ z2,
                                                  const float* __restrict__ srm28,
                                                  float* __restrict__ out) {
    __shared__ float tb[192];
    __shared__ float zb[350 * 11 + 16];   // stride 11: break bank alignment
    __shared__ float ab[352 * 10];
    int b = blockIdx.x, tid = threadIdx.x;
    if (tid < 192) tb[tid] = srm28[tid];
    const float* zp = z2 + (size_t)b * T * NO;
    for (int i = tid; i < T * NO; i += 256) {
        int t = i / NO, o = i - t * NO;
        zb[t * 11 + o] = zp[i];
    }
    __syncthreads();
    if (tid < 220) {
        int tt = tid / 10, o = tid - tt * 10;
        int t0 = tt * 16;
        float acc[16];
        #pragma unroll
        for (int r = 0; r < 16; ++r) acc[r] = 0.f;
        float c[16];
        #pragma unroll
        for (int r = 0; r < 16; ++r) c[r] = tb[r + 127];
        for (int oo = 0; oo < 8; ++oo) {
            #pragma unroll
            for (int j = 0; j < 16; ++j) {
                int dd = oo * 16 + j;
                int tau = t0 - 99 + dd;
                float v = (tau >= 0 && tau < T) ? zb[tau * 11 + o] : 0.f;
                #pragma unroll
                for (int r = 0; r < 16; ++r) acc[r] += c[r] * v;
                #pragma unroll
                for (int r = 15; r > 0; --r) c[r] = c[r - 1];
                int ci = 126 - dd;
                c[0] = tb[ci < 0 ? 0 : ci];
            }
        }
        #pragma unroll
        for (int r = 0; r < 16; ++r) {
            int t = t0 + r;
            if (t < T) ab[t * 10 + o] = acc[r];
        }
    }
    __syncthreads();
    if (tid < NO) {
        int o = tid;
        float A = 0.f, Bs = 0.f;
        float* op = out + ((size_t)b * NO + o) * T;
        for (int t = 0; t < T; ++t) {
            float mem = ab[t * 10 + o] - CREF * Bs;
            float sp = (mem >= THETA) ? 1.0f : 0.0f;
            A = sp + BETA * A;
            Bs = BETA * (Bs + A);
            op[t] = sp;
        }
    }
}

extern "C" void kernel_launch(void* const* d_in, const int* in_sizes, int n_in,
                              void* d_out, int out_size, void* d_ws, size_t ws_size,
                              hipStream_t stream) {
    const float* x  = (const float*)d_in[0];
    const float* W1 = (const float*)d_in[1];
    const float* W2 = (const float*)d_in[2];
    char* ws = (char*)d_ws;
    float*    W1T  = (float*)(ws + OFF_W1T);
    uint64_t* mask = (uint64_t*)(ws + OFF_MASK);
    float*    srm  = (float*)(ws + OFF_SRM);
    float*    z1   = (float*)(ws + OFF_Z1);
    float*    a1   = (float*)(ws + OFF_A1);
    float*    s1   = z1;                       // reuse: z1 dead after fir1
    float*    z2   = (float*)(ws + OFF_Z2);    // reuse: a1 dead after scan1
    float*    out  = (float*)d_out;

    hipLaunchKernelGGL(k_prep,            dim3(2049),         dim3(256), 0, stream, x, W1, W1T, mask, srm);
    hipLaunchKernelGGL(k_z1,              dim3(BT),           dim3(64),  0, stream, mask, W1T, z1);
    hipLaunchKernelGGL(k_fir1,            dim3(B, 2, 22),     dim3(64),  0, stream, z1, a1, srm);
    hipLaunchKernelGGL((k_scan_t<NH, 1>), dim3((B*NH)/64),    dim3(64),  0, stream, a1, s1);
    hipLaunchKernelGGL(k_z2,              dim3(BT),           dim3(64),  0, stream, s1, W2, z2);
    hipLaunchKernelGGL(k_fir2scan,        dim3(B),            dim3(256), 0, stream, z2, srm, out);
}